// Round 3
// baseline (63.062 us; speedup 1.0000x reference)
//
#include <hip/hip_runtime.h>
#include <math.h>

#define BB 8
#define LX 128
#define LY 512
#define DD 256

// ws layout (floats):
//   A    [B][LX][D]                        @ 0
//   Ct2  [B][D/4][LY][4]                   @ CT2_OFF
//   part [B][8][16][16][D]  (xg,yc,xi)     @ PART_OFF
//   pml  [B][8][16][16]     (l sums)       @ PML_OFF
#define A_ELEMS    (BB * LX * DD)                 // 262144
#define CT2_OFF    A_ELEMS
#define CT2_ELEMS  (BB * (DD / 4) * LY * 4)       // 1048576
#define PART_OFF   (CT2_OFF + CT2_ELEMS)          // 1310720
#define PART_ELEMS (BB * 8 * 16 * 16 * DD)        // 4194304
#define PML_OFF    (PART_OFF + PART_ELEMS)        // 5505024

// ---------------------------------------------------------------------------
// Kernel 1: fused GEMMs, 16x128 tiles, grid 640, register-prefetch pipeline.
//   wgs 0..127   : A[r, cols] = x_row @ W1[:D] + b1
//   wgs 128..639 : Ct2[b][d/4][y][d%4] = y_row @ W1[D:]
// ---------------------------------------------------------------------------
__global__ __launch_bounds__(256) void gemm_kernel(
    const float* __restrict__ x, const float* __restrict__ y,
    const float* __restrict__ W1, const float* __restrict__ b1,
    float* __restrict__ ws)
{
    __shared__ float sA[32][20];    // [k][row], 16 rows padded
    __shared__ float sW[32][128];   // [k][col]

    const int g  = blockIdx.x;
    const int t  = threadIdx.x;
    const int tc = t & 31;          // cols col0 + 4tc .. +3
    const int tr = t >> 5;          // rows 2tr, 2tr+1

    const bool isA = (g < 128);
    const float* inp;
    const float* wbase;
    int row0, col0;
    if (isA) { col0 = (g & 1) * 128;  row0 = (g >> 1) * 16;  inp = x; wbase = W1; }
    else     { int h = g - 128; col0 = (h & 1) * 128; row0 = (h >> 1) * 16; inp = y; wbase = W1 + DD * DD; }

    const int srow = t >> 3, skq = t & 7;     // input-stage coords (t<128 only)

    float4 areg = {0.f, 0.f, 0.f, 0.f};
    float4 wreg[4];

    // prologue: prefetch k0 = 0
    if (t < 128) areg = *(const float4*)(inp + (size_t)(row0 + srow) * DD + 4 * skq);
    #pragma unroll
    for (int i = 0; i < 4; ++i) {
        int flat = t + i * 256; int kk = flat >> 5, c4 = flat & 31;
        wreg[i] = *(const float4*)(wbase + (size_t)kk * DD + col0 + 4 * c4);
    }

    float acc[2][4];
    #pragma unroll
    for (int i = 0; i < 2; ++i)
        #pragma unroll
        for (int j = 0; j < 4; ++j) acc[i][j] = 0.f;

    for (int k0 = 0; k0 < DD; k0 += 32) {
        __syncthreads();
        if (t < 128) {
            sA[4*skq + 0][srow] = areg.x;
            sA[4*skq + 1][srow] = areg.y;
            sA[4*skq + 2][srow] = areg.z;
            sA[4*skq + 3][srow] = areg.w;
        }
        #pragma unroll
        for (int i = 0; i < 4; ++i) {
            int flat = t + i * 256; int kk = flat >> 5, c4 = flat & 31;
            *(float4*)&sW[kk][4*c4] = wreg[i];
        }
        __syncthreads();

        if (k0 + 32 < DD) {   // prefetch next K-step; lands under the compute below
            if (t < 128) areg = *(const float4*)(inp + (size_t)(row0 + srow) * DD + (k0 + 32) + 4 * skq);
            #pragma unroll
            for (int i = 0; i < 4; ++i) {
                int flat = t + i * 256; int kk = flat >> 5, c4 = flat & 31;
                wreg[i] = *(const float4*)(wbase + (size_t)(k0 + 32 + kk) * DD + col0 + 4 * c4);
            }
        }

        #pragma unroll
        for (int k = 0; k < 32; ++k) {
            const float a0 = sA[k][2*tr], a1 = sA[k][2*tr + 1];
            const float4 w4 = *(const float4*)&sW[k][4*tc];
            acc[0][0] = fmaf(a0, w4.x, acc[0][0]);
            acc[0][1] = fmaf(a0, w4.y, acc[0][1]);
            acc[0][2] = fmaf(a0, w4.z, acc[0][2]);
            acc[0][3] = fmaf(a0, w4.w, acc[0][3]);
            acc[1][0] = fmaf(a1, w4.x, acc[1][0]);
            acc[1][1] = fmaf(a1, w4.y, acc[1][1]);
            acc[1][2] = fmaf(a1, w4.z, acc[1][2]);
            acc[1][3] = fmaf(a1, w4.w, acc[1][3]);
        }
    }

    if (isA) {
        const float4 bv = *(const float4*)(b1 + col0 + 4 * tc);
        #pragma unroll
        for (int i = 0; i < 2; ++i) {
            const int r = row0 + 2 * tr + i;
            float4 o;
            o.x = acc[i][0] + bv.x; o.y = acc[i][1] + bv.y;
            o.z = acc[i][2] + bv.z; o.w = acc[i][3] + bv.w;
            *(float4*)(ws + (size_t)r * DD + col0 + 4 * tc) = o;
        }
    } else {
        const int dq = (col0 >> 2) + tc;
        #pragma unroll
        for (int i = 0; i < 2; ++i) {
            const int ry = row0 + 2 * tr + i;           // [0,4096)
            const int bb = ry >> 9, yy = ry & 511;
            float4 o = {acc[i][0], acc[i][1], acc[i][2], acc[i][3]};
            *(float4*)(ws + CT2_OFF + (((size_t)(bb * 64 + dq) * 512 + yy) << 2)) = o;
        }
    }
}

// ---------------------------------------------------------------------------
// Kernel 2: partial attention (no-max exp). grid 1024 =
//   (b = bid&7) x (xg: 16 x-rows) x (yc: 32-y chunk). 256 threads.
// Wave w owns rows 4w..4w+3; lane = (y in chunk) x (d half).
// ---------------------------------------------------------------------------
__global__ __launch_bounds__(256, 4) void score_kernel(
    const float* __restrict__ yin, const int* __restrict__ ymask,
    const float* __restrict__ W2, const float* __restrict__ b2,
    float* __restrict__ ws)
{
    __shared__ float sa[16][DD];    // a = hx + b1 for the 16 x rows (16KB)
    __shared__ float sw2[DD];       // 1KB
    __shared__ float sp[16][32];    // exp values (2KB)
    __shared__ float slds[16];

    const int t  = threadIdx.x;
    const int b  = blockIdx.x & 7;
    const int r  = blockIdx.x >> 3;     // [0,128)
    const int xg = r & 7;
    const int yc = r >> 3;              // [0,16)

    {   // 16 contiguous A rows = 1024 float4
        const float4* src = (const float4*)(ws + (size_t)(b * LX + xg * 16) * DD);
        float4* dst = (float4*)sa;
        dst[t]       = src[t];
        dst[t + 256] = src[t + 256];
        dst[t + 512] = src[t + 512];
        dst[t + 768] = src[t + 768];
    }
    if (t < 64) *(float4*)&sw2[4*t] = *(const float4*)(W2 + 4 * t);
    const float b2v = b2[0];
    __syncthreads();

    const int lane = t & 63;
    const int xh   = t >> 6;            // wave -> rows 4xh..4xh+3
    const int yy   = lane & 31;
    const int dh   = lane >> 5;         // d half
    const int y    = yc * 32 + yy;

    float s0 = 0.f, s1 = 0.f, s2 = 0.f, s3 = 0.f;
    const float4* ct  = (const float4*)(ws + CT2_OFF) + ((size_t)b * 64 + dh * 32) * 512 + y;
    const float4* a4  = (const float4*)&sa[4 * xh][0];   // rows stride 64 float4
    const float4* sw4 = (const float4*)sw2 + dh * 32;
    const int dqb = dh * 32;

    #pragma unroll 2
    for (int dqi = 0; dqi < 32; ++dqi) {
        const float4 c  = ct[(size_t)dqi * 512];
        const float4 w4 = sw4[dqi];
        const float4 a0 = a4[dqb + dqi];
        const float4 a1 = a4[dqb + dqi + 64];
        const float4 a2 = a4[dqb + dqi + 128];
        const float4 a3 = a4[dqb + dqi + 192];
        s0 = fmaf(fmaxf(a0.x + c.x, 0.f), w4.x, s0);
        s0 = fmaf(fmaxf(a0.y + c.y, 0.f), w4.y, s0);
        s0 = fmaf(fmaxf(a0.z + c.z, 0.f), w4.z, s0);
        s0 = fmaf(fmaxf(a0.w + c.w, 0.f), w4.w, s0);
        s1 = fmaf(fmaxf(a1.x + c.x, 0.f), w4.x, s1);
        s1 = fmaf(fmaxf(a1.y + c.y, 0.f), w4.y, s1);
        s1 = fmaf(fmaxf(a1.z + c.z, 0.f), w4.z, s1);
        s1 = fmaf(fmaxf(a1.w + c.w, 0.f), w4.w, s1);
        s2 = fmaf(fmaxf(a2.x + c.x, 0.f), w4.x, s2);
        s2 = fmaf(fmaxf(a2.y + c.y, 0.f), w4.y, s2);
        s2 = fmaf(fmaxf(a2.z + c.z, 0.f), w4.z, s2);
        s2 = fmaf(fmaxf(a2.w + c.w, 0.f), w4.w, s2);
        s3 = fmaf(fmaxf(a3.x + c.x, 0.f), w4.x, s3);
        s3 = fmaf(fmaxf(a3.y + c.y, 0.f), w4.y, s3);
        s3 = fmaf(fmaxf(a3.z + c.z, 0.f), w4.z, s3);
        s3 = fmaf(fmaxf(a3.w + c.w, 0.f), w4.w, s3);
    }
    // merge the two d-halves
    s0 += __shfl_xor(s0, 32);
    s1 += __shfl_xor(s1, 32);
    s2 += __shfl_xor(s2, 32);
    s3 += __shfl_xor(s3, 32);

    const bool msk = ymask[(size_t)b * LY + y] != 0;
    const float p0 = msk ? 0.f : __expf(s0 + b2v);
    const float p1 = msk ? 0.f : __expf(s1 + b2v);
    const float p2 = msk ? 0.f : __expf(s2 + b2v);
    const float p3 = msk ? 0.f : __expf(s3 + b2v);

    float l0 = p0, l1 = p1, l2 = p2, l3 = p3;   // sum within each 32-half
    #pragma unroll
    for (int off = 16; off; off >>= 1) {
        l0 += __shfl_xor(l0, off);
        l1 += __shfl_xor(l1, off);
        l2 += __shfl_xor(l2, off);
        l3 += __shfl_xor(l3, off);
    }
    if (lane < 32) {
        sp[4*xh + 0][yy] = p0;
        sp[4*xh + 1][yy] = p1;
        sp[4*xh + 2][yy] = p2;
        sp[4*xh + 3][yy] = p3;
    }
    if (lane == 0) {
        slds[4*xh + 0] = l0; slds[4*xh + 1] = l1;
        slds[4*xh + 2] = l2; slds[4*xh + 3] = l3;
    }
    __syncthreads();

    // ---- partial context: thread owns d = t, 16 rows ---------------------
    float acc[16];
    #pragma unroll
    for (int i = 0; i < 16; ++i) acc[i] = 0.f;
    const float* yb = yin + ((size_t)b * LY + yc * 32) * DD;
    for (int yq = 0; yq < 8; ++yq) {
        const float v0 = yb[(size_t)(4*yq + 0) * DD + t];
        const float v1 = yb[(size_t)(4*yq + 1) * DD + t];
        const float v2 = yb[(size_t)(4*yq + 2) * DD + t];
        const float v3 = yb[(size_t)(4*yq + 3) * DD + t];
        #pragma unroll
        for (int xi = 0; xi < 16; ++xi) {
            const float4 wv = *(const float4*)&sp[xi][4*yq];  // wave-broadcast
            acc[xi] = fmaf(wv.x, v0, acc[xi]);
            acc[xi] = fmaf(wv.y, v1, acc[xi]);
            acc[xi] = fmaf(wv.z, v2, acc[xi]);
            acc[xi] = fmaf(wv.w, v3, acc[xi]);
        }
    }

    float* pb = ws + PART_OFF + (((size_t)(b * 8 + xg) * 16 + yc) * 16) * DD;
    #pragma unroll
    for (int xi = 0; xi < 16; ++xi) pb[(size_t)xi * DD + t] = acc[xi];
    if (t < 16) ws[PML_OFF + ((size_t)(b * 8 + xg) * 16 + yc) * 16 + t] = slds[t];
}

// ---------------------------------------------------------------------------
// Kernel 3: linear combine of the 16 y-chunk partials per (b, x) row. grid 1024.
// ---------------------------------------------------------------------------
__global__ __launch_bounds__(256) void combine_kernel(
    const float* __restrict__ ws, float* __restrict__ out)
{
    const int t = threadIdx.x;
    const int b = blockIdx.x & 7;
    const int xrow = blockIdx.x >> 3;      // [0,128)
    const int xg = xrow >> 4, xi = xrow & 15;

    // part row index for chunk c: (b*8+xg)*256 + c*16 + xi
    const size_t base = (size_t)(b * 8 + xg) * 256 + xi;

    float L = 0.f;
    #pragma unroll
    for (int c = 0; c < 16; ++c) L += ws[PML_OFF + base + 16 * c];

    float acc = 0.f;
    #pragma unroll
    for (int c = 0; c < 16; ++c)
        acc += ws[PART_OFF + (base + 16 * c) * DD + t];

    out[((size_t)(b * LX + xrow)) * DD + t] = acc * (1.f / L);
}

// ---------------------------------------------------------------------------
extern "C" void kernel_launch(void* const* d_in, const int* in_sizes, int n_in,
                              void* d_out, int out_size, void* d_ws, size_t ws_size,
                              hipStream_t stream) {
    const float* x     = (const float*)d_in[0];
    const float* y     = (const float*)d_in[1];
    const int*   ymask = (const int*)  d_in[2];
    const float* W1    = (const float*)d_in[3];
    const float* b1    = (const float*)d_in[4];
    const float* W2    = (const float*)d_in[5];
    const float* b2    = (const float*)d_in[6];
    float* ws  = (float*)d_ws;
    float* out = (float*)d_out;

    hipLaunchKernelGGL(gemm_kernel, dim3(640), dim3(256), 0, stream, x, y, W1, b1, ws);
    hipLaunchKernelGGL(score_kernel, dim3(1024), dim3(256), 0, stream, y, ymask, W2, b2, ws);
    hipLaunchKernelGGL(combine_kernel, dim3(1024), dim3(256), 0, stream, ws, out);
}

// Round 4
// 52.203 us; speedup vs baseline: 1.2080x; 1.2080x over previous
//
#include <hip/hip_runtime.h>
#include <math.h>

#define BB 8
#define LX 128
#define LY 512
#define DD 256

// ws layout (floats):
//   A    [B][LX][D]                         @ 0
//   Ct2  [B][D/4][LY][4]                    @ CT2_OFF
//   part [B][8][8][16][D]   (xg,yc,xi)      @ PART_OFF
//   pml  [B][8][8][16][2]   (m,l)           @ PML_OFF
#define A_ELEMS    (BB * LX * DD)                 // 262144
#define CT2_OFF    A_ELEMS
#define CT2_ELEMS  (BB * (DD / 4) * LY * 4)       // 1048576
#define PART_OFF   (CT2_OFF + CT2_ELEMS)          // 1310720
#define PART_ELEMS (BB * 8 * 8 * 16 * DD)         // 4194304
#define PML_OFF    (PART_OFF + PART_ELEMS)        // 5505024

// ---------------------------------------------------------------------------
// Kernel 1: fused GEMMs, 16x128 tiles, grid 640 (round-2 version, known good).
//   wgs 0..127   : A[r, cols] = x_row @ W1[:D] + b1
//   wgs 128..639 : Ct2[b][d/4][y][d%4] = y_row @ W1[D:]
// ---------------------------------------------------------------------------
__global__ __launch_bounds__(256) void gemm_kernel(
    const float* __restrict__ x, const float* __restrict__ y,
    const float* __restrict__ W1, const float* __restrict__ b1,
    float* __restrict__ ws)
{
    __shared__ float sA[32][20];    // [k][row], 16 rows padded
    __shared__ float sW[32][128];   // [k][col]

    const int g  = blockIdx.x;
    const int t  = threadIdx.x;
    const int tc = t & 31;          // cols col0 + 4tc .. +3
    const int tr = t >> 5;          // rows 2tr, 2tr+1

    const bool isA = (g < 128);
    const float* inp;
    const float* wbase;
    int row0, col0;
    if (isA) { col0 = (g & 1) * 128;  row0 = (g >> 1) * 16;  inp = x; wbase = W1; }
    else     { int h = g - 128; col0 = (h & 1) * 128; row0 = (h >> 1) * 16; inp = y; wbase = W1 + DD * DD; }

    float acc[2][4];
    #pragma unroll
    for (int i = 0; i < 2; ++i)
        #pragma unroll
        for (int j = 0; j < 4; ++j) acc[i][j] = 0.f;

    for (int k0 = 0; k0 < DD; k0 += 32) {
        __syncthreads();
        if (t < 128) {                       // stage 16x32 input block, transposed
            int row = t >> 3, kq = t & 7;
            const float4 v = *(const float4*)(inp + (size_t)(row0 + row) * DD + k0 + 4 * kq);
            sA[4*kq + 0][row] = v.x;
            sA[4*kq + 1][row] = v.y;
            sA[4*kq + 2][row] = v.z;
            sA[4*kq + 3][row] = v.w;
        }
        #pragma unroll
        for (int i = 0; i < 4; ++i) {        // stage 32x128 W block
            int flat = t + i * 256;          // float4 index over [32][32]
            int kk = flat >> 5, c4 = flat & 31;
            *(float4*)&sW[kk][4*c4] = *(const float4*)(wbase + (size_t)(k0 + kk) * DD + col0 + 4 * c4);
        }
        __syncthreads();
        #pragma unroll
        for (int k = 0; k < 32; ++k) {
            const float a0 = sA[k][2*tr], a1 = sA[k][2*tr + 1];
            const float4 w4 = *(const float4*)&sW[k][4*tc];
            acc[0][0] = fmaf(a0, w4.x, acc[0][0]);
            acc[0][1] = fmaf(a0, w4.y, acc[0][1]);
            acc[0][2] = fmaf(a0, w4.z, acc[0][2]);
            acc[0][3] = fmaf(a0, w4.w, acc[0][3]);
            acc[1][0] = fmaf(a1, w4.x, acc[1][0]);
            acc[1][1] = fmaf(a1, w4.y, acc[1][1]);
            acc[1][2] = fmaf(a1, w4.z, acc[1][2]);
            acc[1][3] = fmaf(a1, w4.w, acc[1][3]);
        }
    }

    if (isA) {
        const float4 bv = *(const float4*)(b1 + col0 + 4 * tc);
        #pragma unroll
        for (int i = 0; i < 2; ++i) {
            const int r = row0 + 2 * tr + i;
            float4 o;
            o.x = acc[i][0] + bv.x; o.y = acc[i][1] + bv.y;
            o.z = acc[i][2] + bv.z; o.w = acc[i][3] + bv.w;
            *(float4*)(ws + (size_t)r * DD + col0 + 4 * tc) = o;
        }
    } else {
        const int dq = (col0 >> 2) + tc;
        #pragma unroll
        for (int i = 0; i < 2; ++i) {
            const int ry = row0 + 2 * tr + i;           // [0,4096)
            const int bb = ry >> 9, yy = ry & 511;
            float4 o = {acc[i][0], acc[i][1], acc[i][2], acc[i][3]};
            *(float4*)(ws + CT2_OFF + (((size_t)(bb * 64 + dq) * 512 + yy) << 2)) = o;
        }
    }
}

// ---------------------------------------------------------------------------
// Kernel 2: partial attention, LDS-free / barrier-free.
// grid 512 = (b = bid&7) x (xg: 16-row group) x (yc: 64-y chunk). 256 thr.
// Wave w owns rows row0..row0+3 (wave-uniform -> A,W2 via scalar loads);
// lane = y within chunk. p-values stay in registers; phase 2 via shfl.
// ---------------------------------------------------------------------------
__global__ __launch_bounds__(256) void score_kernel(
    const float* __restrict__ yin, const int* __restrict__ ymask,
    const float* __restrict__ W2, const float* __restrict__ b2,
    const float* __restrict__ Ain, const float* __restrict__ Ct,
    float* __restrict__ part, float* __restrict__ pml)
{
    const int t    = threadIdx.x;
    const int lane = t & 63;
    const int w    = __builtin_amdgcn_readfirstlane(t >> 6);  // wave id, SGPR
    const int b    = blockIdx.x & 7;
    const int r    = blockIdx.x >> 3;    // [0,64)
    const int xg   = r & 7;              // 16-row group
    const int yc   = r >> 3;             // [0,8) 64-y chunk
    const int y    = yc * 64 + lane;
    const int row0 = xg * 16 + w * 4;    // first of this wave's 4 rows (in [0,128))

    const float4* A4  = (const float4*)(Ain + ((size_t)b * LX + row0) * DD);  // rows stride 64 f4
    const float4* W24 = (const float4*)W2;
    const float4* ct  = (const float4*)Ct + ((size_t)b * 64) * 512 + y;
    const float b2v = b2[0];

    float s0a=0.f,s0b=0.f,s1a=0.f,s1b=0.f,s2a=0.f,s2b=0.f,s3a=0.f,s3b=0.f;

    #pragma unroll 2
    for (int dq = 0; dq < 64; ++dq) {
        const float4 c  = ct[(size_t)dq * 512];   // per-lane y, coalesced 1KB
        const float4 w4 = W24[dq];                // uniform -> SGPR
        const float4 a0 = A4[dq];                 // uniform -> SGPR
        const float4 a1 = A4[dq + 64];
        const float4 a2 = A4[dq + 128];
        const float4 a3 = A4[dq + 192];
        s0a = fmaf(fmaxf(a0.x + c.x, 0.f), w4.x, s0a);
        s0b = fmaf(fmaxf(a0.y + c.y, 0.f), w4.y, s0b);
        s0a = fmaf(fmaxf(a0.z + c.z, 0.f), w4.z, s0a);
        s0b = fmaf(fmaxf(a0.w + c.w, 0.f), w4.w, s0b);
        s1a = fmaf(fmaxf(a1.x + c.x, 0.f), w4.x, s1a);
        s1b = fmaf(fmaxf(a1.y + c.y, 0.f), w4.y, s1b);
        s1a = fmaf(fmaxf(a1.z + c.z, 0.f), w4.z, s1a);
        s1b = fmaf(fmaxf(a1.w + c.w, 0.f), w4.w, s1b);
        s2a = fmaf(fmaxf(a2.x + c.x, 0.f), w4.x, s2a);
        s2b = fmaf(fmaxf(a2.y + c.y, 0.f), w4.y, s2b);
        s2a = fmaf(fmaxf(a2.z + c.z, 0.f), w4.z, s2a);
        s2b = fmaf(fmaxf(a2.w + c.w, 0.f), w4.w, s2b);
        s3a = fmaf(fmaxf(a3.x + c.x, 0.f), w4.x, s3a);
        s3b = fmaf(fmaxf(a3.y + c.y, 0.f), w4.y, s3b);
        s3a = fmaf(fmaxf(a3.z + c.z, 0.f), w4.z, s3a);
        s3b = fmaf(fmaxf(a3.w + c.w, 0.f), w4.w, s3b);
    }

    const bool msk = ymask[(size_t)b * LY + y] != 0;
    float sc0 = msk ? -1e30f : (s0a + s0b + b2v);
    float sc1 = msk ? -1e30f : (s1a + s1b + b2v);
    float sc2 = msk ? -1e30f : (s2a + s2b + b2v);
    float sc3 = msk ? -1e30f : (s3a + s3b + b2v);

    float m0 = sc0, m1 = sc1, m2 = sc2, m3 = sc3;
    #pragma unroll
    for (int off = 32; off; off >>= 1) {
        m0 = fmaxf(m0, __shfl_xor(m0, off));
        m1 = fmaxf(m1, __shfl_xor(m1, off));
        m2 = fmaxf(m2, __shfl_xor(m2, off));
        m3 = fmaxf(m3, __shfl_xor(m3, off));
    }
    const float p0 = msk ? 0.f : __expf(sc0 - m0);
    const float p1 = msk ? 0.f : __expf(sc1 - m1);
    const float p2 = msk ? 0.f : __expf(sc2 - m2);
    const float p3 = msk ? 0.f : __expf(sc3 - m3);
    float l0 = p0, l1 = p1, l2 = p2, l3 = p3;
    #pragma unroll
    for (int off = 32; off; off >>= 1) {
        l0 += __shfl_xor(l0, off);
        l1 += __shfl_xor(l1, off);
        l2 += __shfl_xor(l2, off);
        l3 += __shfl_xor(l3, off);
    }

    // ---- phase 2: partial context, p broadcast by shfl (no LDS) ----------
    float4 acc0 = {0,0,0,0}, acc1 = {0,0,0,0}, acc2 = {0,0,0,0}, acc3 = {0,0,0,0};
    const float4* yb4 = (const float4*)(yin + ((size_t)b * LY + yc * 64) * DD) + lane;
    #pragma unroll 8
    for (int yy = 0; yy < 64; ++yy) {
        const float4 v = yb4[(size_t)yy * 64];    // lane owns d-quad 4*lane..+3
        const float q0 = __shfl(p0, yy);
        const float q1 = __shfl(p1, yy);
        const float q2 = __shfl(p2, yy);
        const float q3 = __shfl(p3, yy);
        acc0.x = fmaf(q0, v.x, acc0.x); acc0.y = fmaf(q0, v.y, acc0.y);
        acc0.z = fmaf(q0, v.z, acc0.z); acc0.w = fmaf(q0, v.w, acc0.w);
        acc1.x = fmaf(q1, v.x, acc1.x); acc1.y = fmaf(q1, v.y, acc1.y);
        acc1.z = fmaf(q1, v.z, acc1.z); acc1.w = fmaf(q1, v.w, acc1.w);
        acc2.x = fmaf(q2, v.x, acc2.x); acc2.y = fmaf(q2, v.y, acc2.y);
        acc2.z = fmaf(q2, v.z, acc2.z); acc2.w = fmaf(q2, v.w, acc2.w);
        acc3.x = fmaf(q3, v.x, acc3.x); acc3.y = fmaf(q3, v.y, acc3.y);
        acc3.z = fmaf(q3, v.z, acc3.z); acc3.w = fmaf(q3, v.w, acc3.w);
    }

    float* pb = part + ((size_t)(b * 8 + xg) * 8 + yc) * 16 * DD;
    const int lr = w * 4;                         // local row of this wave
    *(float4*)(pb + (size_t)(lr + 0) * DD + 4 * lane) = acc0;
    *(float4*)(pb + (size_t)(lr + 1) * DD + 4 * lane) = acc1;
    *(float4*)(pb + (size_t)(lr + 2) * DD + 4 * lane) = acc2;
    *(float4*)(pb + (size_t)(lr + 3) * DD + 4 * lane) = acc3;
    if (lane == 0) {
        float* ml = pml + ((size_t)(b * 8 + xg) * 8 + yc) * 32 + 2 * lr;
        ml[0] = m0; ml[1] = l0;
        ml[2] = m1; ml[3] = l1;
        ml[4] = m2; ml[5] = l2;
        ml[6] = m3; ml[7] = l3;
    }
}

// ---------------------------------------------------------------------------
// Kernel 3: combine the 8 y-chunk partials per (b, x) row. grid 1024.
// ---------------------------------------------------------------------------
__global__ __launch_bounds__(256) void combine_kernel(
    const float* __restrict__ part, const float* __restrict__ pml,
    float* __restrict__ out)
{
    const int t = threadIdx.x;
    const int b = blockIdx.x & 7;
    const int x = blockIdx.x >> 3;      // [0,128)
    const int xg = x >> 4, xi = x & 15;

    float mv[8], lv[8];
    float M = -3.4e38f;
    #pragma unroll
    for (int c = 0; c < 8; ++c) {
        const float* ml = pml + ((size_t)(b * 8 + xg) * 8 + c) * 32 + 2 * xi;
        mv[c] = ml[0];
        lv[c] = ml[1];
        M = fmaxf(M, mv[c]);
    }
    float L = 0.f, scl[8];
    #pragma unroll
    for (int c = 0; c < 8; ++c) { scl[c] = __expf(mv[c] - M); L = fmaf(scl[c], lv[c], L); }

    float acc = 0.f;
    #pragma unroll
    for (int c = 0; c < 8; ++c) {
        const float* pb = part + (((size_t)(b * 8 + xg) * 8 + c) * 16 + xi) * DD;
        acc = fmaf(scl[c], pb[t], acc);
    }
    out[((size_t)(b * LX + x)) * DD + t] = acc / L;
}

// ---------------------------------------------------------------------------
extern "C" void kernel_launch(void* const* d_in, const int* in_sizes, int n_in,
                              void* d_out, int out_size, void* d_ws, size_t ws_size,
                              hipStream_t stream) {
    const float* x     = (const float*)d_in[0];
    const float* y     = (const float*)d_in[1];
    const int*   ymask = (const int*)  d_in[2];
    const float* W1    = (const float*)d_in[3];
    const float* b1    = (const float*)d_in[4];
    const float* W2    = (const float*)d_in[5];
    const float* b2    = (const float*)d_in[6];
    float* ws  = (float*)d_ws;
    float* out = (float*)d_out;

    hipLaunchKernelGGL(gemm_kernel, dim3(640), dim3(256), 0, stream, x, y, W1, b1, ws);
    hipLaunchKernelGGL(score_kernel, dim3(512), dim3(256), 0, stream,
                       y, ymask, W2, b2, ws, ws + CT2_OFF, ws + PART_OFF, ws + PML_OFF);
    hipLaunchKernelGGL(combine_kernel, dim3(1024), dim3(256), 0, stream,
                       ws + PART_OFF, ws + PML_OFF, out);
}

// Round 5
// 47.779 us; speedup vs baseline: 1.3199x; 1.0926x over previous
//
#include <hip/hip_runtime.h>
#include <math.h>

#define BB 8
#define LX 128
#define LY 512
#define DD 256

// ws layout (floats):
//   A    [B][LX][D]                          @ 0
//   Ct2  [B][D/4][LY][4]                     @ CT2_OFF
//   part [B][16][8][8][D]   (xg,yc,xi)       @ PART_OFF   (8 MB)
//   pml  [B][16][8][8]      (l sums)         @ PML_OFF
#define A_ELEMS    (BB * LX * DD)                 // 262144
#define CT2_OFF    A_ELEMS
#define CT2_ELEMS  (BB * (DD / 4) * LY * 4)       // 1048576
#define PART_OFF   (CT2_OFF + CT2_ELEMS)          // 1310720
#define PART_ELEMS (BB * 16 * 8 * 8 * DD)         // 2097152
#define PML_OFF    (PART_OFF + PART_ELEMS)        // 3407872

// ---------------------------------------------------------------------------
// Kernel 1: fused GEMMs, 16x128 tiles, grid 640 (round-2 version, known good).
//   wgs 0..127   : A[r, cols] = x_row @ W1[:D] + b1
//   wgs 128..639 : Ct2[b][d/4][y][d%4] = y_row @ W1[D:]
// ---------------------------------------------------------------------------
__global__ __launch_bounds__(256) void gemm_kernel(
    const float* __restrict__ x, const float* __restrict__ y,
    const float* __restrict__ W1, const float* __restrict__ b1,
    float* __restrict__ ws)
{
    __shared__ float sA[32][20];    // [k][row], 16 rows padded
    __shared__ float sW[32][128];   // [k][col]

    const int g  = blockIdx.x;
    const int t  = threadIdx.x;
    const int tc = t & 31;          // cols col0 + 4tc .. +3
    const int tr = t >> 5;          // rows 2tr, 2tr+1

    const bool isA = (g < 128);
    const float* inp;
    const float* wbase;
    int row0, col0;
    if (isA) { col0 = (g & 1) * 128;  row0 = (g >> 1) * 16;  inp = x; wbase = W1; }
    else     { int h = g - 128; col0 = (h & 1) * 128; row0 = (h >> 1) * 16; inp = y; wbase = W1 + DD * DD; }

    float acc[2][4];
    #pragma unroll
    for (int i = 0; i < 2; ++i)
        #pragma unroll
        for (int j = 0; j < 4; ++j) acc[i][j] = 0.f;

    for (int k0 = 0; k0 < DD; k0 += 32) {
        __syncthreads();
        if (t < 128) {                       // stage 16x32 input block, transposed
            int row = t >> 3, kq = t & 7;
            const float4 v = *(const float4*)(inp + (size_t)(row0 + row) * DD + k0 + 4 * kq);
            sA[4*kq + 0][row] = v.x;
            sA[4*kq + 1][row] = v.y;
            sA[4*kq + 2][row] = v.z;
            sA[4*kq + 3][row] = v.w;
        }
        #pragma unroll
        for (int i = 0; i < 4; ++i) {        // stage 32x128 W block
            int flat = t + i * 256;          // float4 index over [32][32]
            int kk = flat >> 5, c4 = flat & 31;
            *(float4*)&sW[kk][4*c4] = *(const float4*)(wbase + (size_t)(k0 + kk) * DD + col0 + 4 * c4);
        }
        __syncthreads();
        #pragma unroll
        for (int k = 0; k < 32; ++k) {
            const float a0 = sA[k][2*tr], a1 = sA[k][2*tr + 1];
            const float4 w4 = *(const float4*)&sW[k][4*tc];
            acc[0][0] = fmaf(a0, w4.x, acc[0][0]);
            acc[0][1] = fmaf(a0, w4.y, acc[0][1]);
            acc[0][2] = fmaf(a0, w4.z, acc[0][2]);
            acc[0][3] = fmaf(a0, w4.w, acc[0][3]);
            acc[1][0] = fmaf(a1, w4.x, acc[1][0]);
            acc[1][1] = fmaf(a1, w4.y, acc[1][1]);
            acc[1][2] = fmaf(a1, w4.z, acc[1][2]);
            acc[1][3] = fmaf(a1, w4.w, acc[1][3]);
        }
    }

    if (isA) {
        const float4 bv = *(const float4*)(b1 + col0 + 4 * tc);
        #pragma unroll
        for (int i = 0; i < 2; ++i) {
            const int r = row0 + 2 * tr + i;
            float4 o;
            o.x = acc[i][0] + bv.x; o.y = acc[i][1] + bv.y;
            o.z = acc[i][2] + bv.z; o.w = acc[i][3] + bv.w;
            *(float4*)(ws + (size_t)r * DD + col0 + 4 * tc) = o;
        }
    } else {
        const int dq = (col0 >> 2) + tc;
        #pragma unroll
        for (int i = 0; i < 2; ++i) {
            const int ry = row0 + 2 * tr + i;           // [0,4096)
            const int bb = ry >> 9, yy = ry & 511;
            float4 o = {acc[i][0], acc[i][1], acc[i][2], acc[i][3]};
            *(float4*)(ws + CT2_OFF + (((size_t)(bb * 64 + dq) * 512 + yy) << 2)) = o;
        }
    }
}

// ---------------------------------------------------------------------------
// Kernel 2: partial attention. LDS-free, DS-free, barrier-free, no-max exp.
// grid 1024 = (b = bid&7) x (xg: 8-row group, 16 of them) x (yc: 64-y chunk, 8).
// 256 threads = 4 waves; wave w owns rows xg*8 + 2w, +1 (A,W2 wave-uniform ->
// scalar loads). lane = y within chunk. Phase-2 broadcast via v_readlane.
// ---------------------------------------------------------------------------
__global__ __launch_bounds__(256) void score_kernel(
    const float* __restrict__ yin, const int* __restrict__ ymask,
    const float* __restrict__ W2, const float* __restrict__ b2,
    const float* __restrict__ Ain, const float* __restrict__ Ct,
    float* __restrict__ part, float* __restrict__ pml)
{
    const int t    = threadIdx.x;
    const int lane = t & 63;
    const int w    = __builtin_amdgcn_readfirstlane(t >> 6);  // wave id, SGPR
    const int b    = blockIdx.x & 7;
    const int r    = blockIdx.x >> 3;    // [0,128)
    const int xg   = r & 15;             // 8-row group
    const int yc   = r >> 4;             // [0,8) 64-y chunk
    const int y    = yc * 64 + lane;
    const int row0 = xg * 8 + w * 2;     // this wave's first row in [0,128)

    const bool msk = ymask[(size_t)b * LY + y] != 0;

    const float4* A4  = (const float4*)(Ain + ((size_t)b * LX + row0) * DD);  // rows: +64 f4
    const float4* W24 = (const float4*)W2;
    const float4* ct  = (const float4*)Ct + ((size_t)b * 64) * 512 + y;
    const float b2v = b2[0];

    float s0a = 0.f, s0b = 0.f, s1a = 0.f, s1b = 0.f;

    #pragma unroll 4
    for (int dq = 0; dq < 64; ++dq) {
        const float4 c  = ct[(size_t)dq * 512];   // per-lane y, coalesced 1KB/wave
        const float4 w4 = W24[dq];                // wave-uniform -> s_load
        const float4 a0 = A4[dq];                 // wave-uniform -> s_load
        const float4 a1 = A4[dq + 64];
        s0a = fmaf(fmaxf(a0.x + c.x, 0.f), w4.x, s0a);
        s0b = fmaf(fmaxf(a0.y + c.y, 0.f), w4.y, s0b);
        s0a = fmaf(fmaxf(a0.z + c.z, 0.f), w4.z, s0a);
        s0b = fmaf(fmaxf(a0.w + c.w, 0.f), w4.w, s0b);
        s1a = fmaf(fmaxf(a1.x + c.x, 0.f), w4.x, s1a);
        s1b = fmaf(fmaxf(a1.y + c.y, 0.f), w4.y, s1b);
        s1a = fmaf(fmaxf(a1.z + c.z, 0.f), w4.z, s1a);
        s1b = fmaf(fmaxf(a1.w + c.w, 0.f), w4.w, s1b);
    }

    const float p0 = msk ? 0.f : __expf(s0a + s0b + b2v);
    const float p1 = msk ? 0.f : __expf(s1a + s1b + b2v);

    // row l-sums (only reduction in the kernel; off the critical path)
    float l0 = p0, l1 = p1;
    #pragma unroll
    for (int off = 32; off; off >>= 1) {
        l0 += __shfl_xor(l0, off);
        l1 += __shfl_xor(l1, off);
    }

    // ---- phase 2: partial context; p broadcast via v_readlane (VALU pipe)
    const int pi0 = __float_as_int(p0);
    const int pi1 = __float_as_int(p1);
    float4 acc0 = {0.f, 0.f, 0.f, 0.f}, acc1 = {0.f, 0.f, 0.f, 0.f};
    const float4* yb4 = (const float4*)(yin + ((size_t)b * LY + yc * 64) * DD) + lane;

    #pragma unroll 8
    for (int yy = 0; yy < 64; ++yy) {
        const float4 v = yb4[(size_t)yy * 64];    // lane owns d-quad 4*lane..+3
        const float q0 = __int_as_float(__builtin_amdgcn_readlane(pi0, yy));
        const float q1 = __int_as_float(__builtin_amdgcn_readlane(pi1, yy));
        acc0.x = fmaf(q0, v.x, acc0.x); acc0.y = fmaf(q0, v.y, acc0.y);
        acc0.z = fmaf(q0, v.z, acc0.z); acc0.w = fmaf(q0, v.w, acc0.w);
        acc1.x = fmaf(q1, v.x, acc1.x); acc1.y = fmaf(q1, v.y, acc1.y);
        acc1.z = fmaf(q1, v.z, acc1.z); acc1.w = fmaf(q1, v.w, acc1.w);
    }

    float* pb = part + (((size_t)(b * 16 + xg) * 8 + yc) * 8 + 2 * w) * DD;
    *(float4*)(pb + 4 * lane)      = acc0;
    *(float4*)(pb + DD + 4 * lane) = acc1;
    if (lane == 0) {
        float* ml = pml + ((size_t)(b * 16 + xg) * 8 + yc) * 8 + 2 * w;
        ml[0] = l0;
        ml[1] = l1;
    }
}

// ---------------------------------------------------------------------------
// Kernel 3: linear combine of the 8 y-chunk partials per (b, x) row. grid 1024.
// ---------------------------------------------------------------------------
__global__ __launch_bounds__(256) void combine_kernel(
    const float* __restrict__ part, const float* __restrict__ pml,
    float* __restrict__ out)
{
    const int t = threadIdx.x;
    const int b = blockIdx.x & 7;
    const int x = blockIdx.x >> 3;      // [0,128)
    const int xg = x >> 3, xi = x & 7;

    const size_t base = (size_t)(b * 16 + xg) * 64 + xi;   // row index into [..][8][8]

    float L = 0.f;
    #pragma unroll
    for (int c = 0; c < 8; ++c) L += pml[base + 8 * c];

    float acc = 0.f;
    #pragma unroll
    for (int c = 0; c < 8; ++c)
        acc += part[(base + 8 * c) * DD + t];

    out[((size_t)(b * LX + x)) * DD + t] = acc / L;
}

// ---------------------------------------------------------------------------
extern "C" void kernel_launch(void* const* d_in, const int* in_sizes, int n_in,
                              void* d_out, int out_size, void* d_ws, size_t ws_size,
                              hipStream_t stream) {
    const float* x     = (const float*)d_in[0];
    const float* y     = (const float*)d_in[1];
    const int*   ymask = (const int*)  d_in[2];
    const float* W1    = (const float*)d_in[3];
    const float* b1    = (const float*)d_in[4];
    const float* W2    = (const float*)d_in[5];
    const float* b2    = (const float*)d_in[6];
    float* ws  = (float*)d_ws;
    float* out = (float*)d_out;

    hipLaunchKernelGGL(gemm_kernel, dim3(640), dim3(256), 0, stream, x, y, W1, b1, ws);
    hipLaunchKernelGGL(score_kernel, dim3(1024), dim3(256), 0, stream,
                       y, ymask, W2, b2, ws, ws + CT2_OFF, ws + PART_OFF, ws + PML_OFF);
    hipLaunchKernelGGL(combine_kernel, dim3(1024), dim3(256), 0, stream,
                       ws + PART_OFF, ws + PML_OFF, out);
}